// Round 2
// baseline (1667.562 us; speedup 1.0000x reference)
//
#include <hip/hip_runtime.h>
#include <cstdint>
#include <cmath>

#define B_ 4
#define N_ 1024
#define P_ 42
#define D_ 96
#define PD_ (P_ * D_)     // 4032
#define KNN_ 8
#define KNODE_ 8
#define KPRE 16           // fp32 pre-selection width (f64 rescored to 8)
#define NCAND (KNODE_ * P_)  // 336
#define OUTP (P_ + KNN_)  // 50
#define EPS_ 1e-7

// ---------------------------------------------------------------------------
// Kernel 1: token norms and node norms, float64 (exact ranking path).
// one wave per node
// ---------------------------------------------------------------------------
__global__ __launch_bounds__(64) void k_norms(const float* __restrict__ h,
                                              double* __restrict__ inv_tok_d,
                                              float* __restrict__ inv_node_f,
                                              double* __restrict__ inv_node_d) {
    const int node = blockIdx.x;   // b*N + n
    const int l = threadIdx.x;     // 0..63
    const float* base = h + (size_t)node * PD_;
    double node_sq = 0.0;
    for (int p = 0; p < P_; ++p) {
        const float* t = base + p * D_;
        double v0 = (double)t[l];
        double s = v0 * v0;                       // exact (24+24 <= 53 bits)
        if (l < 32) { double v1 = (double)t[l + 64]; s += v1 * v1; }
#pragma unroll
        for (int off = 1; off < 64; off <<= 1) s += __shfl_xor(s, off);
        if (l == 0) inv_tok_d[node * P_ + p] = 1.0 / (sqrt(s) + EPS_);
        node_sq += s;
    }
    if (l == 0) {
        double inv = 1.0 / (sqrt(node_sq) + EPS_);
        inv_node_d[node] = inv;
        inv_node_f[node] = (float)inv;
    }
}

// ---------------------------------------------------------------------------
// Kernel 2: sim[b] = scaled (flat . flat^T), diag zeroed.  fp32 PRE-SELECTOR.
// tiles 64(M) x 128(N) x 32(K), 256 threads, micro 4x8. 512 blocks = 2/CU.
// ---------------------------------------------------------------------------
#define BM 64
#define BN 128
#define BK 32

__global__ __launch_bounds__(256, 2) void k_simgemm(const float* __restrict__ h,
                                                    const float* __restrict__ inv_node,
                                                    float* __restrict__ sim) {
    const int b  = blockIdx.z;
    const int mt = blockIdx.y;   // 0..15 row tiles (64 rows)
    const int nt = blockIdx.x;   // 0..7  col tiles (128 cols)
    const float* A = h + (size_t)b * N_ * PD_;

    __shared__ float As[BK][68];
    __shared__ float Bs[BK][132];

    const int tid = threadIdx.x;
    const int tm = tid >> 4;    // 0..15 -> 4 rows each
    const int tn = tid & 15;    // 0..15 -> cols tn*4 and 64+tn*4

    float acc[4][8];
#pragma unroll
    for (int i = 0; i < 4; ++i)
#pragma unroll
        for (int j = 0; j < 8; ++j) acc[i][j] = 0.f;

    float4 ra[2], rb[4];

    auto loadA = [&](int t) {
#pragma unroll
        for (int u = 0; u < 2; ++u) {
            int q = tid + 256 * u;          // 0..511
            int i = q >> 3, kk4 = (q & 7) << 2;
            ra[u] = *(const float4*)(A + (size_t)(mt * BM + i) * PD_ + t * BK + kk4);
        }
    };
    auto loadB = [&](int t) {
#pragma unroll
        for (int u = 0; u < 4; ++u) {
            int q = tid + 256 * u;          // 0..1023
            int j = q >> 3, kk4 = (q & 7) << 2;
            rb[u] = *(const float4*)(A + (size_t)(nt * BN + j) * PD_ + t * BK + kk4);
        }
    };
    auto storeA = [&]() {
#pragma unroll
        for (int u = 0; u < 2; ++u) {
            int q = tid + 256 * u;
            int i = q >> 3, kk4 = (q & 7) << 2;
            As[kk4 + 0][i] = ra[u].x; As[kk4 + 1][i] = ra[u].y;
            As[kk4 + 2][i] = ra[u].z; As[kk4 + 3][i] = ra[u].w;
        }
    };
    auto storeB = [&]() {
#pragma unroll
        for (int u = 0; u < 4; ++u) {
            int q = tid + 256 * u;
            int j = q >> 3, kk4 = (q & 7) << 2;
            Bs[kk4 + 0][j] = rb[u].x; Bs[kk4 + 1][j] = rb[u].y;
            Bs[kk4 + 2][j] = rb[u].z; Bs[kk4 + 3][j] = rb[u].w;
        }
    };

    loadA(0); loadB(0);
    storeA(); storeB();
    __syncthreads();

    const int KT = PD_ / BK;   // 126
    for (int t = 0; t < KT; ++t) {
        if (t + 1 < KT) { loadA(t + 1); loadB(t + 1); }   // prefetch to regs
#pragma unroll 8
        for (int kk = 0; kk < BK; ++kk) {
            float4 av = *(const float4*)&As[kk][tm << 2];
            float4 b0 = *(const float4*)&Bs[kk][tn << 2];
            float4 b1 = *(const float4*)&Bs[kk][64 + (tn << 2)];
            float a[4] = {av.x, av.y, av.z, av.w};
            float bb[8] = {b0.x, b0.y, b0.z, b0.w, b1.x, b1.y, b1.z, b1.w};
#pragma unroll
            for (int i = 0; i < 4; ++i)
#pragma unroll
                for (int j = 0; j < 8; ++j)
                    acc[i][j] = fmaf(a[i], bb[j], acc[i][j]);
        }
        __syncthreads();
        if (t + 1 < KT) { storeA(); storeB(); __syncthreads(); }
    }

    const int row0 = mt * BM + (tm << 2);
    const int c0 = nt * BN + (tn << 2);
    float invc[8];
#pragma unroll
    for (int j = 0; j < 4; ++j) {
        invc[j]     = inv_node[(b << 10) + c0 + j];
        invc[4 + j] = inv_node[(b << 10) + c0 + 64 + j];
    }
#pragma unroll
    for (int i = 0; i < 4; ++i) {
        const int row = row0 + i;
        const float ir = inv_node[(b << 10) + row];
        float4 v0, v1;
        v0.x = (row == c0 + 0) ? 0.f : acc[i][0] * ir * invc[0];
        v0.y = (row == c0 + 1) ? 0.f : acc[i][1] * ir * invc[1];
        v0.z = (row == c0 + 2) ? 0.f : acc[i][2] * ir * invc[2];
        v0.w = (row == c0 + 3) ? 0.f : acc[i][3] * ir * invc[3];
        v1.x = (row == c0 + 64) ? 0.f : acc[i][4] * ir * invc[4];
        v1.y = (row == c0 + 65) ? 0.f : acc[i][5] * ir * invc[5];
        v1.z = (row == c0 + 66) ? 0.f : acc[i][6] * ir * invc[6];
        v1.w = (row == c0 + 67) ? 0.f : acc[i][7] * ir * invc[7];
        float* Crow = sim + ((size_t)(b << 10) + row) * N_;
        *(float4*)(Crow + c0) = v0;
        *(float4*)(Crow + c0 + 64) = v1;
    }
}

// ---------------------------------------------------------------------------
// Kernel 3: per-row fp32 top-16 pre-selection. 1 wave per row.
// (fp32 error ~1e-8 << true gap rank8..rank16 ~5e-3, so top-16 surely
//  contains the exact top-8)
// ---------------------------------------------------------------------------
__global__ __launch_bounds__(256) void k_topk(const float* __restrict__ sim,
                                              int* __restrict__ idx16) {
    const int row = blockIdx.x * 4 + threadIdx.y;   // 0..4095
    const int l = threadIdx.x;                      // 0..63
    const float* s = sim + (size_t)row * N_;
    float v[16];
#pragma unroll
    for (int j = 0; j < 16; ++j) v[j] = s[l + (j << 6)];
    for (int k = 0; k < KPRE; ++k) {
        float bv = v[0]; int bj = 0;
#pragma unroll
        for (int j = 1; j < 16; ++j)
            if (v[j] > bv) { bv = v[j]; bj = j; }
        int bm = l + (bj << 6);
#pragma unroll
        for (int off = 1; off < 64; off <<= 1) {
            float ov = __shfl_xor(bv, off);
            int om = __shfl_xor(bm, off);
            if (ov > bv || (ov == bv && om < bm)) { bv = ov; bm = om; }
        }
        if (l == (bm & 63)) v[bm >> 6] = -INFINITY;
        if (l == 0) idx16[row * KPRE + k] = bm;
    }
}

// ---------------------------------------------------------------------------
// Kernel 3b: float64 rescore of the 16 candidates -> exact ranked top-8.
// one block (4 waves) per row; wave wy handles candidate slots wy*4..wy*4+3.
// ---------------------------------------------------------------------------
__global__ __launch_bounds__(256) void k_rescore(const float* __restrict__ h,
                                                 const double* __restrict__ inv_node_d,
                                                 const int* __restrict__ idx16,
                                                 int* __restrict__ idx8) {
    const int row = blockIdx.x;        // 0..4095
    const int b = row >> 10;
    const int l = threadIdx.x;         // 0..63
    const int wy = threadIdx.y;        // 0..3

    __shared__ double sc[KPRE];
    __shared__ int cid[KPRE];

    const float* x = h + (size_t)row * PD_;
    const double invr = inv_node_d[row];

    for (int c = 0; c < 4; ++c) {
        const int slot = wy * 4 + c;
        const int cand = idx16[row * KPRE + slot];
        const float* y = h + ((size_t)(b << 10) + cand) * PD_;
        double s = 0.0;
        for (int e = l; e < PD_; e += 64)
            s = fma((double)x[e], (double)y[e], s);   // products exact in f64
#pragma unroll
        for (int off = 1; off < 64; off <<= 1) s += __shfl_xor(s, off);
        if (l == 0) {
            sc[slot] = s * invr * inv_node_d[(b << 10) + cand];
            cid[slot] = cand;
        }
    }
    __syncthreads();

    if (l == 0 && wy == 0) {
        double v[KPRE]; int c[KPRE];
#pragma unroll
        for (int j = 0; j < KPRE; ++j) { v[j] = sc[j]; c[j] = cid[j]; }
        for (int k = 0; k < KNN_; ++k) {
            int bj = 0;
#pragma unroll
            for (int j = 1; j < KPRE; ++j)
                if (v[j] > v[bj] || (v[j] == v[bj] && c[j] < c[bj])) bj = j;
            idx8[row * KNN_ + k] = c[bj];
            v[bj] = -1e300;
        }
    }
}

// ---------------------------------------------------------------------------
// Kernel 4: token-level sub-KNN (f64 ranking) + Linear -> out[:, :, 42:50, :]
// one block (4 waves) per (b, n) row.
// ---------------------------------------------------------------------------
__global__ __launch_bounds__(256) void k_subknn(const float* __restrict__ h,
                                                const double* __restrict__ inv_tok_d,
                                                const int* __restrict__ idx,
                                                const float* __restrict__ W,
                                                const float* __restrict__ bias,
                                                const float* __restrict__ ntok,
                                                float* __restrict__ out) {
    const int row = blockIdx.x;        // b*N + n
    const int b = row >> 10;
    const int l = threadIdx.x;         // 0..63
    const int wy = threadIdx.y;        // 0..3
    const int tid = wy * 64 + l;

    __shared__ float Wl[D_][D_ + 1];
    __shared__ float qv[D_];
    __shared__ double ssim[NCAND];
    __shared__ int tsel[8];
    __shared__ float stok[8][D_];

    for (int q = tid; q < D_ * D_; q += 256) Wl[q / D_][q % D_] = W[q];
    const float* qp = h + ((size_t)row * P_ + (P_ - 1)) * D_;
    if (tid < D_) qv[tid] = qp[tid];
    __syncthreads();

    const double invq = inv_tok_d[row * P_ + (P_ - 1)];

    // phase B: 336 candidate token cosine sims in f64 (2 per wave per pass)
    const int half = l >> 5;
    const int l32 = l & 31;
    for (int pass = 0; pass < 42; ++pass) {
        const int t = pass * 8 + wy * 2 + half;   // 0..335
        const int nj = idx[row * 8 + t / P_];
        const int p = t % P_;
        const float* tp = h + (((size_t)(b << 10) + nj) * P_ + p) * D_;
        double s = (double)qv[l32] * (double)tp[l32];
        s = fma((double)qv[l32 + 32], (double)tp[l32 + 32], s);
        s = fma((double)qv[l32 + 64], (double)tp[l32 + 64], s);
#pragma unroll
        for (int off = 1; off < 32; off <<= 1) s += __shfl_xor(s, off);
        if (l32 == 0)
            ssim[t] = s * invq * inv_tok_d[((b << 10) + nj) * P_ + p];
    }
    __syncthreads();

    // phase C: top-8 of 336 (wave 0), ties -> lower flattened index
    if (wy == 0) {
        double v[6];
#pragma unroll
        for (int j = 0; j < 6; ++j) {
            int t = l + (j << 6);
            v[j] = (t < NCAND) ? ssim[t] : -1e300;
        }
        for (int k = 0; k < 8; ++k) {
            double bv = v[0]; int bj = 0;
#pragma unroll
            for (int j = 1; j < 6; ++j)
                if (v[j] > bv) { bv = v[j]; bj = j; }
            int bt = l + (bj << 6);
#pragma unroll
            for (int off = 1; off < 64; off <<= 1) {
                double ov = __shfl_xor(bv, off);
                int ot = __shfl_xor(bt, off);
                if (ov > bv || (ov == bv && ot < bt)) { bv = ov; bt = ot; }
            }
            if (l == (bt & 63)) v[bt >> 6] = -1e300;
            if (l == 0) tsel[k] = bt;
        }
    }
    __syncthreads();

    // phase D0: gather the 8 selected token vectors to LDS
    for (int q = tid; q < 8 * D_; q += 256) {
        const int k = q / D_, e = q % D_;
        const int t = tsel[k];
        const int nj = idx[row * 8 + t / P_];
        const int p = t % P_;
        stok[k][e] = h[(((size_t)(b << 10) + nj) * P_ + p) * D_ + e];
    }
    __syncthreads();

    // phase D: sk = tok @ W^T + b + neighbor_token (fp32 values)
    const float nt0 = ntok[0];
    const int e2 = (l < 32) ? l + 64 : l;
#pragma unroll
    for (int rep = 0; rep < 2; ++rep) {
        const int k = wy * 2 + rep;
        float acc0 = bias[l] + nt0;
        float acc1 = bias[e2] + nt0;
#pragma unroll 8
        for (int dd = 0; dd < D_; ++dd) {
            const float tv = stok[k][dd];
            acc0 = fmaf(tv, Wl[l][dd], acc0);
            acc1 = fmaf(tv, Wl[e2][dd], acc1);
        }
        float* op = out + ((size_t)row * OUTP + P_ + k) * D_;
        op[l] = acc0;
        if (l < 32) op[l + 64] = acc1;
    }
}

// ---------------------------------------------------------------------------
// Kernel 5: hf = h @ W^T + b  -> out[:, :, 0:42, :]. 64 tokens per block.
// ---------------------------------------------------------------------------
__global__ __launch_bounds__(256) void k_hf(const float* __restrict__ h,
                                            const float* __restrict__ W,
                                            const float* __restrict__ bias,
                                            float* __restrict__ out) {
    const int l = threadIdx.x, wy = threadIdx.y;
    const int tid = wy * 64 + l;
    __shared__ float Wl[D_][D_ + 1];
    __shared__ float tok[4][D_];
    for (int q = tid; q < D_ * D_; q += 256) Wl[q / D_][q % D_] = W[q];
    const int t0 = blockIdx.x * 64;
    const float be0 = bias[l];
    const int e2 = (l < 32) ? l + 64 : l;
    const float be1 = bias[e2];
    __syncthreads();

    for (int r = 0; r < 16; ++r) {
        const int t = t0 + r * 4 + wy;        // global token id
        const float* tp = h + (size_t)t * D_;
        tok[wy][l] = tp[l];
        if (l < 32) tok[wy][l + 64] = tp[l + 64];
        __syncthreads();
        float acc0 = be0, acc1 = be1;
#pragma unroll 8
        for (int dd = 0; dd < D_; ++dd) {
            const float tv = tok[wy][dd];
            acc0 = fmaf(tv, Wl[l][dd], acc0);
            acc1 = fmaf(tv, Wl[e2][dd], acc1);
        }
        const int node = t / P_, p = t % P_;
        float* op = out + ((size_t)node * OUTP + p) * D_;
        op[l] = acc0;
        if (l < 32) op[l + 64] = acc1;
        __syncthreads();
    }
}

// ---------------------------------------------------------------------------
extern "C" void kernel_launch(void* const* d_in, const int* in_sizes, int n_in,
                              void* d_out, int out_size, void* d_ws, size_t ws_size,
                              hipStream_t stream) {
    const float* h    = (const float*)d_in[0];   // [4,1024,42,96]
    const float* W    = (const float*)d_in[1];   // [96,96]
    const float* bias = (const float*)d_in[2];   // [96]
    const float* ntok = (const float*)d_in[3];   // [1,1]
    float* out = (float*)d_out;                  // [4,1024,50,96]

    char* ws = (char*)d_ws;
    double* inv_tok_d  = (double*)ws;                          // 172032 d
    double* inv_node_d = inv_tok_d + (size_t)B_ * N_ * P_;     // 4096 d
    float*  inv_node_f = (float*)(inv_node_d + (size_t)B_ * N_);
    float*  sim        = inv_node_f + (size_t)B_ * N_;         // 4*1024*1024 f
    int*    idx16      = (int*)(sim + (size_t)B_ * N_ * N_);   // 4096*16
    int*    idx8       = idx16 + (size_t)B_ * N_ * KPRE;       // 4096*8

    k_norms<<<B_ * N_, 64, 0, stream>>>(h, inv_tok_d, inv_node_f, inv_node_d);
    k_simgemm<<<dim3(N_ / BN, N_ / BM, B_), 256, 0, stream>>>(h, inv_node_f, sim);
    k_topk<<<(B_ * N_) / 4, dim3(64, 4), 0, stream>>>(sim, idx16);
    k_rescore<<<B_ * N_, dim3(64, 4), 0, stream>>>(h, inv_node_d, idx16, idx8);
    k_subknn<<<B_ * N_, dim3(64, 4), 0, stream>>>(h, inv_tok_d, idx8, W, bias, ntok, out);
    k_hf<<<(B_ * N_ * P_) / 64, dim3(64, 4), 0, stream>>>(h, W, bias, out);
}

// Round 3
// 1091.149 us; speedup vs baseline: 1.5283x; 1.5283x over previous
//
#include <hip/hip_runtime.h>
#include <cstdint>
#include <cmath>

typedef __attribute__((ext_vector_type(8))) short short8;
typedef __attribute__((ext_vector_type(4))) float f32x4;

#define B_ 4
#define N_ 1024
#define P_ 42
#define D_ 96
#define PD_ 4032
#define KNN_ 8
#define KPRE 16           // fp32/bf16-split pre-selection width (f64 rescored to 8)
#define NCAND 336
#define OUTP 50
#define EPS_ 1e-7

// ---------------------------------------------------------------------------
// Kernel 0: split fp32 -> bf16 hi + bf16 lo (RNE).  4 floats/thread.
// ---------------------------------------------------------------------------
__global__ __launch_bounds__(256) void k_convert(const float* __restrict__ h,
                                                 unsigned short* __restrict__ Ah,
                                                 unsigned short* __restrict__ Al) {
    const size_t i = ((size_t)blockIdx.x * 256 + threadIdx.x) * 4;
    float4 x = *(const float4*)(h + i);
    float xs[4] = {x.x, x.y, x.z, x.w};
    unsigned short hs[4], ls[4];
#pragma unroll
    for (int j = 0; j < 4; ++j) {
        unsigned int u = __float_as_uint(xs[j]);
        unsigned int r = u + 0x7fffu + ((u >> 16) & 1u);
        unsigned short hb = (unsigned short)(r >> 16);
        float hf = __uint_as_float((unsigned int)hb << 16);
        float lo = xs[j] - hf;
        unsigned int u2 = __float_as_uint(lo);
        unsigned int r2 = u2 + 0x7fffu + ((u2 >> 16) & 1u);
        hs[j] = hb; ls[j] = (unsigned short)(r2 >> 16);
    }
    uint2 hv, lv;
    hv.x = hs[0] | ((unsigned int)hs[1] << 16); hv.y = hs[2] | ((unsigned int)hs[3] << 16);
    lv.x = ls[0] | ((unsigned int)ls[1] << 16); lv.y = ls[2] | ((unsigned int)ls[3] << 16);
    *(uint2*)(Ah + i) = hv;
    *(uint2*)(Al + i) = lv;
}

// ---------------------------------------------------------------------------
// Kernel 1: token norms and node norms, float64 (exact ranking path).
// ---------------------------------------------------------------------------
__global__ __launch_bounds__(64) void k_norms(const float* __restrict__ h,
                                              double* __restrict__ inv_tok_d,
                                              float* __restrict__ inv_node_f,
                                              double* __restrict__ inv_node_d) {
    const int node = blockIdx.x;   // b*N + n
    const int l = threadIdx.x;     // 0..63
    const float* base = h + (size_t)node * PD_;
    double node_sq = 0.0;
    for (int p = 0; p < P_; ++p) {
        const float* t = base + p * D_;
        double v0 = (double)t[l];
        double s = v0 * v0;
        if (l < 32) { double v1 = (double)t[l + 64]; s += v1 * v1; }
#pragma unroll
        for (int off = 1; off < 64; off <<= 1) s += __shfl_xor(s, off);
        if (l == 0) inv_tok_d[node * P_ + p] = 1.0 / (sqrt(s) + EPS_);
        node_sq += s;
    }
    if (l == 0) {
        double inv = 1.0 / (sqrt(node_sq) + EPS_);
        inv_node_d[node] = inv;
        inv_node_f[node] = (float)inv;
    }
}

// ---------------------------------------------------------------------------
// Kernel 2: sim = scaled (flat . flat^T) via split-bf16 MFMA, diag zeroed.
// 128x128 tile/block, 4 waves (64x64 each), BK=32, double-buffered
// global_load_lds staging, K-major LDS tiles [kb][row][8] (conflict-free).
// C = Ah.Bh^T + Ah.Bl^T + Al.Bh^T  (error ~2^-18 * |x||y|, preselect-safe)
// ---------------------------------------------------------------------------
#define KT_ 126   // 4032/32

__global__ __launch_bounds__(256) void k_gemm(const unsigned short* __restrict__ Ah,
                                              const unsigned short* __restrict__ Al,
                                              const float* __restrict__ inv_node,
                                              float* __restrict__ sim) {
    const int b  = blockIdx.z;
    const int mt = blockIdx.y;   // 0..7
    const int nt = blockIdx.x;   // 0..7
    const int tid = threadIdx.x;
    const int w = tid >> 6, l = tid & 63;
    const int wr = w >> 1, wc = w & 1;
    const int lr = l & 15, kb4 = l >> 4;

    // [buf][tile: Ah,Al,Bh,Bl][kb*1024 + row*8 + j]  (64 KiB total)
    __shared__ __align__(16) unsigned short lds[2][4][4096];

    const size_t bbase = (size_t)b * N_ * PD_;
    const int gm0 = mt * 128, gn0 = nt * 128;

    // per-lane stage source offsets (elements) and per-wave LDS instr bases
    unsigned int offR[2]; int ldso[2];
#pragma unroll
    for (int u = 0; u < 2; ++u) {
        int pi = w * 2 + u;          // 0..7 (1 KiB plane per instr)
        int idx = pi * 64 + l;       // 0..511 -> (kb,row)
        int row = idx & 127, kb = idx >> 7;
        offR[u] = (unsigned int)row * PD_ + kb * 8;
        ldso[u] = pi * 512;          // ushort elements
    }

    const unsigned short* srcs[4] = {
        Ah + bbase + (size_t)gm0 * PD_,
        Al + bbase + (size_t)gm0 * PD_,
        Ah + bbase + (size_t)gn0 * PD_,
        Al + bbase + (size_t)gn0 * PD_ };

    f32x4 acc[4][4];
#pragma unroll
    for (int i = 0; i < 4; ++i)
#pragma unroll
        for (int j = 0; j < 4; ++j) acc[i][j] = (f32x4)0.f;

    auto stage = [&](int buf, int t) {
        const int k0 = t * 32;
#pragma unroll
        for (int T = 0; T < 4; ++T) {
#pragma unroll
            for (int u = 0; u < 2; ++u) {
                const unsigned short* g = srcs[T] + offR[u] + k0;
                unsigned short* lp = (unsigned short*)&lds[buf][T][ldso[u]];
                __builtin_amdgcn_global_load_lds(
                    (const __attribute__((address_space(1))) void*)g,
                    (__attribute__((address_space(3))) void*)lp, 16, 0, 0);
            }
        }
    };

    stage(0, 0);
    asm volatile("s_waitcnt vmcnt(0)" ::: "memory");
    __syncthreads();

    int buf = 0;
    for (int t = 0; t < KT_; ++t) {
        if (t + 1 < KT_) stage(buf ^ 1, t + 1);

        short8 ahf[4], alf[4], bhf[4], blf[4];
        const int rbase = kb4 * 1024;
#pragma unroll
        for (int mi = 0; mi < 4; ++mi) {
            const int ro = rbase + (wr * 64 + mi * 16 + lr) * 8;
            ahf[mi] = *(const short8*)&lds[buf][0][ro];
            alf[mi] = *(const short8*)&lds[buf][1][ro];
        }
#pragma unroll
        for (int ni = 0; ni < 4; ++ni) {
            const int ro = rbase + (wc * 64 + ni * 16 + lr) * 8;
            bhf[ni] = *(const short8*)&lds[buf][2][ro];
            blf[ni] = *(const short8*)&lds[buf][3][ro];
        }
#pragma unroll
        for (int mi = 0; mi < 4; ++mi)
#pragma unroll
            for (int ni = 0; ni < 4; ++ni) {
                acc[mi][ni] = __builtin_amdgcn_mfma_f32_16x16x32_bf16(ahf[mi], bhf[ni], acc[mi][ni], 0, 0, 0);
                acc[mi][ni] = __builtin_amdgcn_mfma_f32_16x16x32_bf16(ahf[mi], blf[ni], acc[mi][ni], 0, 0, 0);
                acc[mi][ni] = __builtin_amdgcn_mfma_f32_16x16x32_bf16(alf[mi], bhf[ni], acc[mi][ni], 0, 0, 0);
            }

        if (t + 1 < KT_) {
            asm volatile("s_waitcnt vmcnt(0)" ::: "memory");
            __syncthreads();
            buf ^= 1;
        }
    }

    // epilogue: scale by inverse node norms, zero diagonal.
    // C/D layout (m89-verified): col = lane&15, row = (lane>>4)*4 + reg
    const int col0 = gn0 + wc * 64;
    const int rowb = gm0 + wr * 64;
    float invc[4];
#pragma unroll
    for (int ni = 0; ni < 4; ++ni)
        invc[ni] = inv_node[(b << 10) + col0 + ni * 16 + lr];
    const int rl = kb4 * 4;
#pragma unroll
    for (int mi = 0; mi < 4; ++mi) {
#pragma unroll
        for (int r = 0; r < 4; ++r) {
            const int row = rowb + mi * 16 + rl + r;
            const float ir = inv_node[(b << 10) + row];
            float* crow = sim + (size_t)((b << 10) + row) * N_;
#pragma unroll
            for (int ni = 0; ni < 4; ++ni) {
                const int col = col0 + ni * 16 + lr;
                crow[col] = (row == col) ? 0.f : acc[mi][ni][r] * ir * invc[ni];
            }
        }
    }
}

// ---------------------------------------------------------------------------
// Kernel 3: per-row top-16 pre-selection. 1 wave per row.
// ---------------------------------------------------------------------------
__global__ __launch_bounds__(256) void k_topk(const float* __restrict__ sim,
                                              int* __restrict__ idx16) {
    const int row = blockIdx.x * 4 + threadIdx.y;   // 0..4095
    const int l = threadIdx.x;                      // 0..63
    const float* s = sim + (size_t)row * N_;
    float v[16];
#pragma unroll
    for (int j = 0; j < 16; ++j) v[j] = s[l + (j << 6)];
    for (int k = 0; k < KPRE; ++k) {
        float bv = v[0]; int bj = 0;
#pragma unroll
        for (int j = 1; j < 16; ++j)
            if (v[j] > bv) { bv = v[j]; bj = j; }
        int bm = l + (bj << 6);
#pragma unroll
        for (int off = 1; off < 64; off <<= 1) {
            float ov = __shfl_xor(bv, off);
            int om = __shfl_xor(bm, off);
            if (ov > bv || (ov == bv && om < bm)) { bv = ov; bm = om; }
        }
        if (l == (bm & 63)) v[bm >> 6] = -INFINITY;
        if (l == 0) idx16[row * KPRE + k] = bm;
    }
}

// ---------------------------------------------------------------------------
// Kernel 3b: float64 rescore of the 16 candidates -> exact ranked top-8.
// float4 gathers; x cached in registers across the 4 candidates per wave.
// ---------------------------------------------------------------------------
__global__ __launch_bounds__(256) void k_rescore(const float* __restrict__ h,
                                                 const double* __restrict__ inv_node_d,
                                                 const int* __restrict__ idx16,
                                                 int* __restrict__ idx8) {
    const int row = blockIdx.x;        // 0..4095
    const int b = row >> 10;
    const int l = threadIdx.x & 63;
    const int wy = threadIdx.x >> 6;   // 0..3

    __shared__ double sc[KPRE];
    __shared__ int cid[KPRE];

    const float4* x4 = (const float4*)(h + (size_t)row * PD_);
    float4 xr[16];
#pragma unroll
    for (int j = 0; j < 16; ++j) {
        int i4 = l + (j << 6);
        xr[j] = (i4 < 1008) ? x4[i4] : make_float4(0.f, 0.f, 0.f, 0.f);
    }
    const double invr = inv_node_d[row];

#pragma unroll
    for (int c = 0; c < 4; ++c) {
        const int slot = wy * 4 + c;
        const int cand = idx16[row * KPRE + slot];
        const float4* y4 = (const float4*)(h + ((size_t)(b << 10) + cand) * PD_);
        double s = 0.0;
#pragma unroll
        for (int j = 0; j < 16; ++j) {
            int i4 = l + (j << 6);
            if (i4 < 1008) {
                float4 yv = y4[i4];
                s = fma((double)xr[j].x, (double)yv.x, s);
                s = fma((double)xr[j].y, (double)yv.y, s);
                s = fma((double)xr[j].z, (double)yv.z, s);
                s = fma((double)xr[j].w, (double)yv.w, s);
            }
        }
#pragma unroll
        for (int off = 1; off < 64; off <<= 1) s += __shfl_xor(s, off);
        if (l == 0) {
            sc[slot] = s * invr * inv_node_d[(b << 10) + cand];
            cid[slot] = cand;
        }
    }
    __syncthreads();

    if (threadIdx.x == 0) {
        double v[KPRE]; int c[KPRE];
#pragma unroll
        for (int j = 0; j < KPRE; ++j) { v[j] = sc[j]; c[j] = cid[j]; }
        for (int k = 0; k < KNN_; ++k) {
            int bj = 0;
#pragma unroll
            for (int j = 1; j < KPRE; ++j)
                if (v[j] > v[bj] || (v[j] == v[bj] && c[j] < c[bj])) bj = j;
            idx8[row * KNN_ + k] = c[bj];
            v[bj] = -1e300;
        }
    }
}

// ---------------------------------------------------------------------------
// Kernel 4: token-level sub-KNN (f64 ranking) + Linear -> out[:, :, 42:50, :]
// ---------------------------------------------------------------------------
__global__ __launch_bounds__(256) void k_subknn(const float* __restrict__ h,
                                                const double* __restrict__ inv_tok_d,
                                                const int* __restrict__ idx,
                                                const float* __restrict__ W,
                                                const float* __restrict__ bias,
                                                const float* __restrict__ ntok,
                                                float* __restrict__ out) {
    const int row = blockIdx.x;        // b*N + n
    const int b = row >> 10;
    const int l = threadIdx.x;         // 0..63
    const int wy = threadIdx.y;        // 0..3
    const int tid = wy * 64 + l;

    __shared__ float Wl[D_][D_ + 1];
    __shared__ float qv[D_];
    __shared__ double ssim[NCAND];
    __shared__ int tsel[8];
    __shared__ float stok[8][D_];

    for (int q = tid; q < D_ * D_; q += 256) Wl[q / D_][q % D_] = W[q];
    const float* qp = h + ((size_t)row * P_ + (P_ - 1)) * D_;
    if (tid < D_) qv[tid] = qp[tid];
    __syncthreads();

    const double invq = inv_tok_d[row * P_ + (P_ - 1)];

    const int half = l >> 5;
    const int l32 = l & 31;
    for (int pass = 0; pass < 42; ++pass) {
        const int t = pass * 8 + wy * 2 + half;   // 0..335
        const int nj = idx[row * 8 + t / P_];
        const int p = t % P_;
        const float* tp = h + (((size_t)(b << 10) + nj) * P_ + p) * D_;
        double s = (double)qv[l32] * (double)tp[l32];
        s = fma((double)qv[l32 + 32], (double)tp[l32 + 32], s);
        s = fma((double)qv[l32 + 64], (double)tp[l32 + 64], s);
#pragma unroll
        for (int off = 1; off < 32; off <<= 1) s += __shfl_xor(s, off);
        if (l32 == 0)
            ssim[t] = s * invq * inv_tok_d[((b << 10) + nj) * P_ + p];
    }
    __syncthreads();

    if (wy == 0) {
        double v[6];
#pragma unroll
        for (int j = 0; j < 6; ++j) {
            int t = l + (j << 6);
            v[j] = (t < NCAND) ? ssim[t] : -1e300;
        }
        for (int k = 0; k < 8; ++k) {
            double bv = v[0]; int bj = 0;
#pragma unroll
            for (int j = 1; j < 6; ++j)
                if (v[j] > bv) { bv = v[j]; bj = j; }
            int bt = l + (bj << 6);
#pragma unroll
            for (int off = 1; off < 64; off <<= 1) {
                double ov = __shfl_xor(bv, off);
                int ot = __shfl_xor(bt, off);
                if (ov > bv || (ov == bv && ot < bt)) { bv = ov; bt = ot; }
            }
            if (l == (bt & 63)) v[bt >> 6] = -1e300;
            if (l == 0) tsel[k] = bt;
        }
    }
    __syncthreads();

    for (int q = tid; q < 8 * D_; q += 256) {
        const int k = q / D_, e = q % D_;
        const int t = tsel[k];
        const int nj = idx[row * 8 + t / P_];
        const int p = t % P_;
        stok[k][e] = h[(((size_t)(b << 10) + nj) * P_ + p) * D_ + e];
    }
    __syncthreads();

    const float nt0 = ntok[0];
    const int e2 = (l < 32) ? l + 64 : l;
#pragma unroll
    for (int rep = 0; rep < 2; ++rep) {
        const int k = wy * 2 + rep;
        float acc0 = bias[l] + nt0;
        float acc1 = bias[e2] + nt0;
#pragma unroll 8
        for (int dd = 0; dd < D_; ++dd) {
            const float tv = stok[k][dd];
            acc0 = fmaf(tv, Wl[l][dd], acc0);
            acc1 = fmaf(tv, Wl[e2][dd], acc1);
        }
        float* op = out + ((size_t)row * OUTP + P_ + k) * D_;
        op[l] = acc0;
        if (l < 32) op[l + 64] = acc1;
    }
}

// ---------------------------------------------------------------------------
// Kernel 5: hf = h @ W^T + b  -> out[:, :, 0:42, :]. 64 tokens per block.
// ---------------------------------------------------------------------------
__global__ __launch_bounds__(256) void k_hf(const float* __restrict__ h,
                                            const float* __restrict__ W,
                                            const float* __restrict__ bias,
                                            float* __restrict__ out) {
    const int l = threadIdx.x, wy = threadIdx.y;
    const int tid = wy * 64 + l;
    __shared__ float Wl[D_][D_ + 1];
    __shared__ float tok[4][D_];
    for (int q = tid; q < D_ * D_; q += 256) Wl[q / D_][q % D_] = W[q];
    const int t0 = blockIdx.x * 64;
    const float be0 = bias[l];
    const int e2 = (l < 32) ? l + 64 : l;
    const float be1 = bias[e2];
    __syncthreads();

    for (int r = 0; r < 16; ++r) {
        const int t = t0 + r * 4 + wy;
        const float* tp = h + (size_t)t * D_;
        tok[wy][l] = tp[l];
        if (l < 32) tok[wy][l + 64] = tp[l + 64];
        __syncthreads();
        float acc0 = be0, acc1 = be1;
#pragma unroll 8
        for (int dd = 0; dd < D_; ++dd) {
            const float tv = tok[wy][dd];
            acc0 = fmaf(tv, Wl[l][dd], acc0);
            acc1 = fmaf(tv, Wl[e2][dd], acc1);
        }
        const int node = t / P_, p = t % P_;
        float* op = out + ((size_t)node * OUTP + p) * D_;
        op[l] = acc0;
        if (l < 32) op[l + 64] = acc1;
        __syncthreads();
    }
}

// ---------------------------------------------------------------------------
extern "C" void kernel_launch(void* const* d_in, const int* in_sizes, int n_in,
                              void* d_out, int out_size, void* d_ws, size_t ws_size,
                              hipStream_t stream) {
    const float* h    = (const float*)d_in[0];   // [4,1024,42,96]
    const float* W    = (const float*)d_in[1];   // [96,96]
    const float* bias = (const float*)d_in[2];   // [96]
    const float* ntok = (const float*)d_in[3];   // [1,1]
    float* out = (float*)d_out;                  // [4,1024,50,96]

    char* ws = (char*)d_ws;
    size_t off = 0;
    double* inv_tok_d  = (double*)(ws + off); off += (size_t)B_ * N_ * P_ * 8;   // 1376256
    double* inv_node_d = (double*)(ws + off); off += (size_t)B_ * N_ * 8;        // 32768
    float*  inv_node_f = (float*)(ws + off);  off += (size_t)B_ * N_ * 4;        // 16384
    float*  sim        = (float*)(ws + off);  off += (size_t)B_ * N_ * N_ * 4;   // 16777216
    int*    idx16      = (int*)(ws + off);    off += (size_t)B_ * N_ * KPRE * 4; // 262144
    int*    idx8       = (int*)(ws + off);    off += (size_t)B_ * N_ * KNN_ * 4; // 131072
    unsigned short* Ahp = (unsigned short*)(ws + off); off += (size_t)B_ * N_ * PD_ * 2;
    unsigned short* Alp = (unsigned short*)(ws + off); off += (size_t)B_ * N_ * PD_ * 2;

    k_convert<<<(B_ * N_ * PD_) / (256 * 4), 256, 0, stream>>>(h, Ahp, Alp);
    k_norms<<<B_ * N_, 64, 0, stream>>>(h, inv_tok_d, inv_node_f, inv_node_d);
    k_gemm<<<dim3(8, 8, B_), 256, 0, stream>>>(Ahp, Alp, inv_node_f, sim);
    k_topk<<<(B_ * N_) / 4, dim3(64, 4), 0, stream>>>(sim, idx16);
    k_rescore<<<B_ * N_, 256, 0, stream>>>(h, inv_node_d, idx16, idx8);
    k_subknn<<<B_ * N_, dim3(64, 4), 0, stream>>>(h, inv_tok_d, idx8, W, bias, ntok, out);
    k_hf<<<(B_ * N_ * P_) / 64, dim3(64, 4), 0, stream>>>(h, W, bias, out);
}

// Round 6
// 662.102 us; speedup vs baseline: 2.5186x; 1.6480x over previous
//
#include <hip/hip_runtime.h>
#include <cstdint>
#include <cmath>

typedef __attribute__((ext_vector_type(8))) short short8;
typedef __attribute__((ext_vector_type(4))) float f32x4;

#define B_ 4
#define N_ 1024
#define P_ 42
#define D_ 96
#define PD_ 4032
#define KNN_ 8
#define KPRE 12           // bf16-split pre-selection width (f64 rescored to 8)
#define NCAND 336
#define OUTP 50
#define EPS_ 1e-7

// ---------------------------------------------------------------------------
// Kernel 0: split fp32 -> bf16 hi + bf16 lo (RNE).  4 floats/thread.
// ---------------------------------------------------------------------------
__global__ __launch_bounds__(256) void k_convert(const float* __restrict__ h,
                                                 unsigned short* __restrict__ Ah,
                                                 unsigned short* __restrict__ Al) {
    const size_t i = ((size_t)blockIdx.x * 256 + threadIdx.x) * 4;
    float4 x = *(const float4*)(h + i);
    float xs[4] = {x.x, x.y, x.z, x.w};
    unsigned short hs[4], ls[4];
#pragma unroll
    for (int j = 0; j < 4; ++j) {
        unsigned int u = __float_as_uint(xs[j]);
        unsigned int r = u + 0x7fffu + ((u >> 16) & 1u);
        unsigned short hb = (unsigned short)(r >> 16);
        float hf = __uint_as_float((unsigned int)hb << 16);
        float lo = xs[j] - hf;
        unsigned int u2 = __float_as_uint(lo);
        unsigned int r2 = u2 + 0x7fffu + ((u2 >> 16) & 1u);
        hs[j] = hb; ls[j] = (unsigned short)(r2 >> 16);
    }
    uint2 hv, lv;
    hv.x = hs[0] | ((unsigned int)hs[1] << 16); hv.y = hs[2] | ((unsigned int)hs[3] << 16);
    lv.x = ls[0] | ((unsigned int)ls[1] << 16); lv.y = ls[2] | ((unsigned int)ls[3] << 16);
    *(uint2*)(Ah + i) = hv;
    *(uint2*)(Al + i) = lv;
}

// ---------------------------------------------------------------------------
// Kernel 0b: split W (96x96) -> bf16 hi/lo.  One block.
// ---------------------------------------------------------------------------
__global__ __launch_bounds__(256) void k_convw(const float* __restrict__ W,
                                               unsigned short* __restrict__ Wh,
                                               unsigned short* __restrict__ Wl) {
    for (int q = threadIdx.x; q < D_ * D_; q += 256) {
        float x = W[q];
        unsigned int u = __float_as_uint(x);
        unsigned int r = u + 0x7fffu + ((u >> 16) & 1u);
        unsigned short hb = (unsigned short)(r >> 16);
        float hf = __uint_as_float((unsigned int)hb << 16);
        float lo = x - hf;
        unsigned int u2 = __float_as_uint(lo);
        unsigned int r2 = u2 + 0x7fffu + ((u2 >> 16) & 1u);
        Wh[q] = hb; Wl[q] = (unsigned short)(r2 >> 16);
    }
}

// ---------------------------------------------------------------------------
// Kernel 1: token norms and node norms, float64, float4 loads.
// one wave per node; 2 tokens per pass (24 active lanes per 32-half).
// ---------------------------------------------------------------------------
__global__ __launch_bounds__(64) void k_norms(const float* __restrict__ h,
                                              double* __restrict__ inv_tok_d,
                                              float* __restrict__ inv_node_f,
                                              double* __restrict__ inv_node_d) {
    const int node = blockIdx.x;   // b*N + n
    const int l = threadIdx.x;     // 0..63
    const int half = l >> 5, l32 = l & 31;
    const float4* base4 = (const float4*)(h + (size_t)node * PD_);
    double acc_node = 0.0;
    for (int pass = 0; pass < 21; ++pass) {
        const int p = pass * 2 + half;
        double s = 0.0;
        if (l32 < 24) {
            float4 v = base4[p * 24 + l32];
            s = (double)v.x * v.x + (double)v.y * v.y
              + (double)v.z * v.z + (double)v.w * v.w;
        }
#pragma unroll
        for (int off = 1; off < 32; off <<= 1) s += __shfl_xor(s, off);
        if (l32 == 0) {
            inv_tok_d[node * P_ + p] = 1.0 / (sqrt(s) + EPS_);
            acc_node += s;
        }
    }
    double other = __shfl_xor(acc_node, 32);
    if (l == 0) {
        double inv = 1.0 / (sqrt(acc_node + other) + EPS_);
        inv_node_d[node] = inv;
        inv_node_f[node] = (float)inv;
    }
}

// ---------------------------------------------------------------------------
// Kernel 2: sim = scaled (flat . flat^T) via split-bf16 MFMA, diag zeroed.
// 128x128 tile/block, 4 waves (64x64 each), BK=32, double-buffered
// global_load_lds staging, K-major LDS tiles [kb][row][8] (conflict-free).
// C = Ah.Bh^T + Ah.Bl^T + Al.Bh^T  (error ~2^-18 * |x||y|, preselect-safe)
// ---------------------------------------------------------------------------
#define KT_ 126   // 4032/32

__global__ __launch_bounds__(256) void k_gemm(const unsigned short* __restrict__ Ah,
                                              const unsigned short* __restrict__ Al,
                                              const float* __restrict__ inv_node,
                                              float* __restrict__ sim) {
    const int b  = blockIdx.z;
    const int mt = blockIdx.y;   // 0..7
    const int nt = blockIdx.x;   // 0..7
    const int tid = threadIdx.x;
    const int w = tid >> 6, l = tid & 63;
    const int wr = w >> 1, wc = w & 1;
    const int lr = l & 15, kb4 = l >> 4;

    __shared__ __align__(16) unsigned short lds[2][4][4096];

    const size_t bbase = (size_t)b * N_ * PD_;
    const int gm0 = mt * 128, gn0 = nt * 128;

    unsigned int offR[2]; int ldso[2];
#pragma unroll
    for (int u = 0; u < 2; ++u) {
        int pi = w * 2 + u;
        int idx = pi * 64 + l;
        int row = idx & 127, kb = idx >> 7;
        offR[u] = (unsigned int)row * PD_ + kb * 8;
        ldso[u] = pi * 512;
    }

    const unsigned short* srcs[4] = {
        Ah + bbase + (size_t)gm0 * PD_,
        Al + bbase + (size_t)gm0 * PD_,
        Ah + bbase + (size_t)gn0 * PD_,
        Al + bbase + (size_t)gn0 * PD_ };

    f32x4 acc[4][4];
#pragma unroll
    for (int i = 0; i < 4; ++i)
#pragma unroll
        for (int j = 0; j < 4; ++j) acc[i][j] = (f32x4)0.f;

    auto stage = [&](int buf, int t) {
        const int k0 = t * 32;
#pragma unroll
        for (int T = 0; T < 4; ++T) {
#pragma unroll
            for (int u = 0; u < 2; ++u) {
                const unsigned short* g = srcs[T] + offR[u] + k0;
                unsigned short* lp = (unsigned short*)&lds[buf][T][ldso[u]];
                __builtin_amdgcn_global_load_lds(
                    (const __attribute__((address_space(1))) void*)g,
                    (__attribute__((address_space(3))) void*)lp, 16, 0, 0);
            }
        }
    };

    stage(0, 0);
    asm volatile("s_waitcnt vmcnt(0)" ::: "memory");
    __syncthreads();

    int buf = 0;
    for (int t = 0; t < KT_; ++t) {
        if (t + 1 < KT_) stage(buf ^ 1, t + 1);

        short8 ahf[4], alf[4], bhf[4], blf[4];
        const int rbase = kb4 * 1024;
#pragma unroll
        for (int mi = 0; mi < 4; ++mi) {
            const int ro = rbase + (wr * 64 + mi * 16 + lr) * 8;
            ahf[mi] = *(const short8*)&lds[buf][0][ro];
            alf[mi] = *(const short8*)&lds[buf][1][ro];
        }
#pragma unroll
        for (int ni = 0; ni < 4; ++ni) {
            const int ro = rbase + (wc * 64 + ni * 16 + lr) * 8;
            bhf[ni] = *(const short8*)&lds[buf][2][ro];
            blf[ni] = *(const short8*)&lds[buf][3][ro];
        }
#pragma unroll
        for (int mi = 0; mi < 4; ++mi)
#pragma unroll
            for (int ni = 0; ni < 4; ++ni) {
                acc[mi][ni] = __builtin_amdgcn_mfma_f32_16x16x32_bf16(ahf[mi], bhf[ni], acc[mi][ni], 0, 0, 0);
                acc[mi][ni] = __builtin_amdgcn_mfma_f32_16x16x32_bf16(ahf[mi], blf[ni], acc[mi][ni], 0, 0, 0);
                acc[mi][ni] = __builtin_amdgcn_mfma_f32_16x16x32_bf16(alf[mi], bhf[ni], acc[mi][ni], 0, 0, 0);
            }

        if (t + 1 < KT_) {
            asm volatile("s_waitcnt vmcnt(0)" ::: "memory");
            __syncthreads();
            buf ^= 1;
        }
    }

    const int col0 = gn0 + wc * 64;
    const int rowb = gm0 + wr * 64;
    float invc[4];
#pragma unroll
    for (int ni = 0; ni < 4; ++ni)
        invc[ni] = inv_node[(b << 10) + col0 + ni * 16 + lr];
    const int rl = kb4 * 4;
#pragma unroll
    for (int mi = 0; mi < 4; ++mi) {
#pragma unroll
        for (int r = 0; r < 4; ++r) {
            const int row = rowb + mi * 16 + rl + r;
            const float ir = inv_node[(b << 10) + row];
            float* crow = sim + (size_t)((b << 10) + row) * N_;
#pragma unroll
            for (int ni = 0; ni < 4; ++ni) {
                const int col = col0 + ni * 16 + lr;
                crow[col] = (row == col) ? 0.f : acc[mi][ni][r] * ir * invc[ni];
            }
        }
    }
}

// ---------------------------------------------------------------------------
// Kernel 3: per-row top-12 pre-selection. 1 wave per row.
// ---------------------------------------------------------------------------
__global__ __launch_bounds__(256) void k_topk(const float* __restrict__ sim,
                                              int* __restrict__ idx12) {
    const int row = blockIdx.x * 4 + threadIdx.y;   // 0..4095
    const int l = threadIdx.x;                      // 0..63
    const float* s = sim + (size_t)row * N_;
    float v[16];
#pragma unroll
    for (int j = 0; j < 16; ++j) v[j] = s[l + (j << 6)];
    for (int k = 0; k < KPRE; ++k) {
        float bv = v[0]; int bj = 0;
#pragma unroll
        for (int j = 1; j < 16; ++j)
            if (v[j] > bv) { bv = v[j]; bj = j; }
        int bm = l + (bj << 6);
#pragma unroll
        for (int off = 1; off < 64; off <<= 1) {
            float ov = __shfl_xor(bv, off);
            int om = __shfl_xor(bm, off);
            if (ov > bv || (ov == bv && om < bm)) { bv = ov; bm = om; }
        }
        if (l == (bm & 63)) v[bm >> 6] = -INFINITY;
        if (l == 0) idx12[row * KPRE + k] = bm;
    }
}

// ---------------------------------------------------------------------------
// Kernel 3b: float64 rescore of the 12 candidates -> exact ranked top-8.
// ---------------------------------------------------------------------------
__global__ __launch_bounds__(256) void k_rescore(const float* __restrict__ h,
                                                 const double* __restrict__ inv_node_d,
                                                 const int* __restrict__ idx12,
                                                 int* __restrict__ idx8) {
    const int row = blockIdx.x;        // 0..4095
    const int b = row >> 10;
    const int l = threadIdx.x & 63;
    const int wy = threadIdx.x >> 6;   // 0..3

    __shared__ double sc[KPRE];
    __shared__ int cid[KPRE];

    const float4* x4 = (const float4*)(h + (size_t)row * PD_);
    float4 xr[16];
#pragma unroll
    for (int j = 0; j < 16; ++j) {
        int i4 = l + (j << 6);
        xr[j] = (i4 < 1008) ? x4[i4] : make_float4(0.f, 0.f, 0.f, 0.f);
    }
    const double invr = inv_node_d[row];

#pragma unroll
    for (int c = 0; c < 3; ++c) {
        const int slot = wy * 3 + c;
        const int cand = idx12[row * KPRE + slot];
        const float4* y4 = (const float4*)(h + ((size_t)(b << 10) + cand) * PD_);
        double s = 0.0;
#pragma unroll
        for (int j = 0; j < 16; ++j) {
            int i4 = l + (j << 6);
            if (i4 < 1008) {
                float4 yv = y4[i4];
                s = fma((double)xr[j].x, (double)yv.x, s);
                s = fma((double)xr[j].y, (double)yv.y, s);
                s = fma((double)xr[j].z, (double)yv.z, s);
                s = fma((double)xr[j].w, (double)yv.w, s);
            }
        }
#pragma unroll
        for (int off = 1; off < 64; off <<= 1) s += __shfl_xor(s, off);
        if (l == 0) {
            sc[slot] = s * invr * inv_node_d[(b << 10) + cand];
            cid[slot] = cand;
        }
    }
    __syncthreads();

    if (threadIdx.x == 0) {
        double v[KPRE]; int c[KPRE];
#pragma unroll
        for (int j = 0; j < KPRE; ++j) { v[j] = sc[j]; c[j] = cid[j]; }
        for (int k = 0; k < KNN_; ++k) {
            int bj = 0;
#pragma unroll
            for (int j = 1; j < KPRE; ++j)
                if (v[j] > v[bj] || (v[j] == v[bj] && c[j] < c[bj])) bj = j;
            idx8[row * KNN_ + k] = c[bj];
            v[bj] = -1e300;
        }
    }
}

// ---------------------------------------------------------------------------
// Kernel 4: token-level sub-KNN sims (f64 ranking) -> sel global token ids.
// One block per row, 4 waves; 8 lanes per candidate token, float4 loads.
// LDS ~2.7 KB -> high occupancy (was 43.5 KB).
// ---------------------------------------------------------------------------
__global__ __launch_bounds__(256) void k_subsim(const float* __restrict__ h,
                                                const double* __restrict__ inv_tok_d,
                                                const int* __restrict__ idx8,
                                                int* __restrict__ sel) {
    const int row = blockIdx.x;        // b*N + n
    const int b = row >> 10;
    const int l = threadIdx.x & 63;
    const int w = threadIdx.x >> 6;    // 0..3
    const int slot = l >> 3, sub = l & 7;

    __shared__ double ssim[NCAND];
    __shared__ int nidx[8];

    if (threadIdx.x < 8) nidx[threadIdx.x] = idx8[row * 8 + threadIdx.x];

    // q fragments in registers: lane covers float4s {sub, sub+8, sub+16}
    const float4* q4 = (const float4*)(h + ((size_t)row * P_ + (P_ - 1)) * D_);
    float4 qf[3];
#pragma unroll
    for (int c = 0; c < 3; ++c) qf[c] = q4[sub + 8 * c];
    const double invq = inv_tok_d[row * P_ + (P_ - 1)];
    __syncthreads();

    for (int pass = 0; pass < 11; ++pass) {
        const int t = pass * 32 + w * 8 + slot;   // group-uniform
        if (t < NCAND) {
            const int kn = t / P_, p = t - kn * P_;
            const int gid = ((b << 10) + nidx[kn]) * P_ + p;
            const float4* y4 = (const float4*)(h + (size_t)gid * D_);
            double s = 0.0;
#pragma unroll
            for (int c = 0; c < 3; ++c) {
                float4 y = y4[sub + 8 * c];
                s = fma((double)qf[c].x, (double)y.x, s);
                s = fma((double)qf[c].y, (double)y.y, s);
                s = fma((double)qf[c].z, (double)y.z, s);
                s = fma((double)qf[c].w, (double)y.w, s);
            }
#pragma unroll
            for (int off = 1; off < 8; off <<= 1) s += __shfl_xor(s, off);
            if (sub == 0) ssim[t] = s * invq * inv_tok_d[gid];
        }
    }
    __syncthreads();

    // top-8 of 336 (wave 0), ties -> lower flattened index; emit global ids
    if (w == 0) {
        double v[6];
#pragma unroll
        for (int j = 0; j < 6; ++j) {
            int t = l + (j << 6);
            v[j] = (t < NCAND) ? ssim[t] : -1e300;
        }
        for (int k = 0; k < 8; ++k) {
            double bv = v[0]; int bj = 0;
#pragma unroll
            for (int j = 1; j < 6; ++j)
                if (v[j] > bv) { bv = v[j]; bj = j; }
            int bt = l + (bj << 6);
#pragma unroll
            for (int off = 1; off < 64; off <<= 1) {
                double ov = __shfl_xor(bv, off);
                int ot = __shfl_xor(bt, off);
                if (ov > bv || (ov == bv && ot < bt)) { bv = ov; bt = ot; }
            }
            if (l == (bt & 63)) v[bt >> 6] = -1e300;
            if (l == 0) {
                const int kn = bt / P_, p = bt - kn * P_;
                sel[row * 8 + k] = ((b << 10) + nidx[kn]) * P_ + p;
            }
        }
    }
}

// ---------------------------------------------------------------------------
// Kernel 5: fused output Linear for BOTH streams via split-bf16 MFMA.
// out[node][0..41] = h tokens @ W^T + b ; out[node][42..49] = sel tokens + ntok.
// One block per node, 4 waves; wave w = M-tile rows w*16.. (rows >=50 dummy).
// ---------------------------------------------------------------------------
__global__ __launch_bounds__(256) void k_out(const unsigned short* __restrict__ Ah,
                                             const unsigned short* __restrict__ Al,
                                             const unsigned short* __restrict__ Wh,
                                             const unsigned short* __restrict__ Wl,
                                             const int* __restrict__ sel,
                                             const float* __restrict__ bias,
                                             const float* __restrict__ ntok,
                                             float* __restrict__ out) {
    const int node = blockIdx.x;            // 0..4095
    const int l = threadIdx.x & 63;
    const int w = threadIdx.x >> 6;         // m-tile
    const int lr = l & 15, kg = l >> 4;     // frag row / k-group
    const int m0 = w * 16;
    const int arow = m0 + lr;               // token row this lane loads A for

    int gid;
    if (arow < P_)            gid = node * P_ + arow;
    else if (arow < OUTP)     gid = sel[node * 8 + (arow - P_)];
    else                      gid = node * P_;     // dummy (discarded)

    const unsigned short* ap_h = Ah + (size_t)gid * D_ + kg * 8;
    const unsigned short* ap_l = Al + (size_t)gid * D_ + kg * 8;
    short8 a_h[3], a_l[3];
#pragma unroll
    for (int kk = 0; kk < 3; ++kk) {
        a_h[kk] = *(const short8*)(ap_h + kk * 32);
        a_l[kk] = *(const short8*)(ap_l + kk * 32);
    }
    const float nt0 = ntok[0];

#pragma unroll
    for (int nt = 0; nt < 6; ++nt) {
        const int n0 = nt * 16;
        const unsigned short* wp_h = Wh + (size_t)(n0 + lr) * D_ + kg * 8;
        const unsigned short* wp_l = Wl + (size_t)(n0 + lr) * D_ + kg * 8;
        f32x4 acc = (f32x4)0.f;
#pragma unroll
        for (int kk = 0; kk < 3; ++kk) {
            short8 b_h = *(const short8*)(wp_h + kk * 32);
            short8 b_l = *(const short8*)(wp_l + kk * 32);
            acc = __builtin_amdgcn_mfma_f32_16x16x32_bf16(a_h[kk], b_h, acc, 0, 0, 0);
            acc = __builtin_amdgcn_mfma_f32_16x16x32_bf16(a_h[kk], b_l, acc, 0, 0, 0);
            acc = __builtin_amdgcn_mfma_f32_16x16x32_bf16(a_l[kk], b_h, acc, 0, 0, 0);
        }
        const int col = n0 + lr;
        const float bcol = bias[col];
#pragma unroll
        for (int r = 0; r < 4; ++r) {
            const int orow = m0 + kg * 4 + r;   // C layout: row=(l>>4)*4+reg
            if (orow < OUTP) {
                float v = acc[r] + bcol + (orow >= P_ ? nt0 : 0.f);
                out[((size_t)node * OUTP + orow) * D_ + col] = v;
            }
        }
    }
}

// ---------------------------------------------------------------------------
extern "C" void kernel_launch(void* const* d_in, const int* in_sizes, int n_in,
                              void* d_out, int out_size, void* d_ws, size_t ws_size,
                              hipStream_t stream) {
    const float* h    = (const float*)d_in[0];   // [4,1024,42,96]
    const float* W    = (const float*)d_in[1];   // [96,96]
    const float* bias = (const float*)d_in[2];   // [96]
    const float* ntok = (const float*)d_in[3];   // [1,1]
    float* out = (float*)d_out;                  // [4,1024,50,96]

    char* ws = (char*)d_ws;
    size_t off = 0;
    double* inv_tok_d  = (double*)(ws + off); off += (size_t)B_ * N_ * P_ * 8;   // 1376256
    double* inv_node_d = (double*)(ws + off); off += (size_t)B_ * N_ * 8;        // 32768
    float*  inv_node_f = (float*)(ws + off);  off += (size_t)B_ * N_ * 4;        // 16384
    float*  sim        = (float*)(ws + off);  off += (size_t)B_ * N_ * N_ * 4;   // 16777216
    int*    idx12      = (int*)(ws + off);    off += (size_t)B_ * N_ * KPRE * 4; // 196608
    int*    idx8       = (int*)(ws + off);    off += (size_t)B_ * N_ * KNN_ * 4; // 131072
    int*    sel        = (int*)(ws + off);    off += (size_t)B_ * N_ * KNN_ * 4; // 131072
    unsigned short* Ahp = (unsigned short*)(ws + off); off += (size_t)B_ * N_ * PD_ * 2;
    unsigned short* Alp = (unsigned short*)(ws + off); off += (size_t)B_ * N_ * PD_ * 2;
    unsigned short* Whp = (unsigned short*)(ws + off); off += (size_t)D_ * D_ * 2;
    unsigned short* Wlp = (unsigned short*)(ws + off); off += (size_t)D_ * D_ * 2;

    k_convert<<<(B_ * N_ * PD_) / (256 * 4), 256, 0, stream>>>(h, Ahp, Alp);
    k_convw<<<1, 256, 0, stream>>>(W, Whp, Wlp);
    k_norms<<<B_ * N_, 64, 0, stream>>>(h, inv_tok_d, inv_node_f, inv_node_d);
    k_gemm<<<dim3(8, 8, B_), 256, 0, stream>>>(Ahp, Alp, inv_node_f, sim);
    k_topk<<<(B_ * N_) / 4, dim3(64, 4), 0, stream>>>(sim, idx12);
    k_rescore<<<B_ * N_, 256, 0, stream>>>(h, inv_node_d, idx12, idx8);
    k_subsim<<<B_ * N_, 256, 0, stream>>>(h, inv_tok_d, idx8, sel);
    k_out<<<B_ * N_, 256, 0, stream>>>(Ahp, Alp, Whp, Wlp, sel, bias, ntok, out);
}